// Round 7
// baseline (1235.817 us; speedup 1.0000x reference)
//
#include <hip/hip_runtime.h>
#include <hip/hip_bf16.h>
#include <stdint.h>

#define NR 8192   // rows (N)
#define ND 1024   // feature dim (D)

typedef __attribute__((ext_vector_type(8))) short bf16x8;  // 8 bf16 = 4 VGPR
typedef __attribute__((ext_vector_type(4))) float f32x4;   // MFMA C/D
typedef __attribute__((ext_vector_type(4))) float fvec4;   // ext-vector float4 (nontemporal ok)
typedef __attribute__((ext_vector_type(8))) unsigned short u16x8;

static __device__ __forceinline__ uint16_t f2bf(float f) {
  union { __hip_bfloat16 h; uint16_t u; } cv;
  cv.h = __float2bfloat16(f);
  return cv.u;
}
static __device__ __forceinline__ float bf2f(uint16_t u) {
  union { uint32_t i; float f; } cv;
  cv.i = ((uint32_t)u) << 16;
  return cv.f;
}

// ---------------- kernel 1: row L2 norm -> normalized bf16 ----------------
__global__ void k_norm(const float* __restrict__ X, uint16_t* __restrict__ Xn) {
  const int row = blockIdx.x;
  const int t = threadIdx.x;                    // 256 threads, 4 floats each
  const float4 v = reinterpret_cast<const float4*>(X + (size_t)row * ND)[t];
  float ss = v.x * v.x + v.y * v.y + v.z * v.z + v.w * v.w;
#pragma unroll
  for (int m = 1; m < 64; m <<= 1) ss += __shfl_xor(ss, m, 64);
  __shared__ float sred[4];
  if ((t & 63) == 0) sred[t >> 6] = ss;
  __syncthreads();
  const float tot = sred[0] + sred[1] + sred[2] + sred[3];
  const float inv = 1.0f / fmaxf(sqrtf(tot), 1e-12f);
  ushort4 o;
  o.x = f2bf(v.x * inv); o.y = f2bf(v.y * inv);
  o.z = f2bf(v.z * inv); o.w = f2bf(v.w * inv);
  reinterpret_cast<ushort4*>(Xn + (size_t)row * ND)[t] = o;
}

// ------------- kernel 1b: feats [NR][ND] f32 -> featsT [ND][NR] bf16 -------------
__global__ void k_transpose(const float* __restrict__ X, uint16_t* __restrict__ XT) {
  __shared__ uint16_t tile[32][33];
  const int ntr = NR / 32;                     // 256 row-tiles
  const int bx = blockIdx.x % ntr;             // row-tile of X
  const int by = blockIdx.x / ntr;             // col(dim)-tile of X
  const int r0 = bx * 32, d0 = by * 32;
  const int t = threadIdx.x;                   // 256
  const int rr = t >> 3, cc = (t & 7) * 4;
  const float4 v = *reinterpret_cast<const float4*>(&X[(size_t)(r0 + rr) * ND + d0 + cc]);
  tile[cc + 0][rr] = f2bf(v.x);
  tile[cc + 1][rr] = f2bf(v.y);
  tile[cc + 2][rr] = f2bf(v.z);
  tile[cc + 3][rr] = f2bf(v.w);
  __syncthreads();
  ushort4 o;
  o.x = tile[rr][cc + 0]; o.y = tile[rr][cc + 1];
  o.z = tile[rr][cc + 2]; o.w = tile[rr][cc + 3];
  *reinterpret_cast<ushort4*>(&XT[(size_t)(d0 + rr) * NR + r0 + cc]) = o;
}

// ---------------- 32-MFMA cluster (one M-half x all N x K=64) ----------------
template <int HALF>
static __device__ __forceinline__ void mfma32(f32x4 (&acc)[8][4],
                                              const bf16x8 (&a_)[4][2],
                                              const bf16x8 (&b_)[4][2]) {
  __builtin_amdgcn_s_setprio(1);
#pragma unroll
  for (int kk = 0; kk < 2; ++kk)
#pragma unroll
    for (int m4 = 0; m4 < 4; ++m4)
#pragma unroll
      for (int n = 0; n < 4; ++n)
        acc[HALF * 4 + m4][n] = __builtin_amdgcn_mfma_f32_16x16x32_bf16(
            a_[m4][kk], b_[n][kk], acc[HALF * 4 + m4][n], 0, 0, 0);
  __builtin_amdgcn_s_setprio(0);
}

#define BAR()  __builtin_amdgcn_s_barrier()
#define LGKM() asm volatile("s_waitcnt lgkmcnt(0)" ::: "memory")
#define VMW8() asm volatile("s_waitcnt vmcnt(8)" ::: "memory")
#define VMW0() asm volatile("s_waitcnt vmcnt(0)" ::: "memory")

// ---------------- 256x256 4-phase BT GEMM core (same as R6) ----------------
template <int EPI, int NKT>
static __device__ __forceinline__ void gemm8_core(
    char* sm,
    const uint16_t* __restrict__ A, int lda,
    const uint16_t* __restrict__ B, int ldb,
    int row0, int col0,
    float* __restrict__ C, int ldc,
    uint16_t* __restrict__ Eo, float* __restrict__ partials, int rb, int cb) {
  const int tid = threadIdx.x;
  const int wid = tid >> 6;
  const int lane = tid & 63;
  const int wr = wid >> 2;            // 0..1  (M wave)
  const int wc = wid & 3;             // 0..3  (N wave)
  const int flane = lane & 15;
  const int kbyte = (lane >> 4) * 16;                 // 16B k-chunk per lane group
  const int swz6 = (flane & 4) << 4;                  // row-bit-2 -> col-bit-6
  const int rowb = flane * 128;

  // staging source geometry (inverse-swizzled global source, linear LDS dest)
  const int colb = ((tid & 7) * 16) ^ (((tid >> 5) & 1) << 6);
  const int r0s = tid >> 3;           // row for load g0; g1 adds 64

  const char* const Abyte = (const char*)A + (size_t)row0 * lda * 2;
  const char* const Bbyte = (const char*)B + (size_t)col0 * ldb * 2;

  f32x4 acc[8][4] = {};
  bf16x8 a_[4][2], b_[4][2];

  auto stage = [&](int d, int isB, int h, int t) {
    const char* gb = isB ? Bbyte : Abyte;
    const int ld2 = (isB ? ldb : lda) * 2;
    const char* g0 = gb + (size_t)(h * 128 + r0s) * ld2 + t * 128 + colb;
    const char* g1 = g0 + (size_t)64 * ld2;
    char* l0 = sm + d * 65536 + isB * 32768 + h * 16384 + (wid << 10);
    __builtin_amdgcn_global_load_lds((const __attribute__((address_space(1))) void*)g0,
                                     (__attribute__((address_space(3))) void*)l0, 16, 0, 0);
    __builtin_amdgcn_global_load_lds((const __attribute__((address_space(1))) void*)g1,
                                     (__attribute__((address_space(3))) void*)(l0 + 8192), 16, 0, 0);
  };
  auto stage4 = [&](int d, int t) {
    stage(d, 0, 0, t); stage(d, 0, 1, t); stage(d, 1, 0, t); stage(d, 1, 1, t);
  };
  auto rdA = [&](int d, int mhalf) {
#pragma unroll
    for (int m4 = 0; m4 < 4; ++m4)
#pragma unroll
      for (int kk = 0; kk < 2; ++kk)
        a_[m4][kk] = *(const bf16x8*)(sm + d * 65536 + wr * 16384 +
                                      (mhalf * 4 + m4) * 2048 + rowb +
                                      ((kbyte + kk * 64) ^ swz6));
  };
  auto rdB = [&](int d) {
#pragma unroll
    for (int n = 0; n < 4; ++n)
#pragma unroll
      for (int kk = 0; kk < 2; ++kk)
        b_[n][kk] = *(const bf16x8*)(sm + d * 65536 + 32768 + (wc >> 1) * 16384 +
                                     (wc & 1) * 8192 + n * 2048 + rowb +
                                     ((kbyte + kk * 64) ^ swz6));
  };

  // prologue: stage d0 <- K-tile 0 (8 load instrs in flight)
  stage4(0, 0);

  const int niter = NKT / 2;
  for (int i = 0; i < niter; ++i) {
    const int t0 = 2 * i, t1 = 2 * i + 1;
    // P1
    stage4(1, t1);
    VMW8();           // wait d0 landed (keep d1's 8 loads in flight)
    BAR();            // publish d0 across waves
    rdA(0, 0); rdB(0);
    LGKM(); mfma32<0>(acc, a_, b_); BAR();
    // P2
    rdA(0, 1);
    LGKM(); mfma32<1>(acc, a_, b_); BAR();
    // P3
    if (t0 + 2 < NKT) { stage4(0, t0 + 2); VMW8(); }
    else { VMW0(); }
    BAR();            // publish d1
    rdA(1, 0); rdB(1);
    LGKM(); mfma32<0>(acc, a_, b_); BAR();
    // P4
    rdA(1, 1);
    LGKM(); mfma32<1>(acc, a_, b_); BAR();
  }

  const int e0 = (lane >> 4) * 4;   // C/D: row=(lane>>4)*4+e, col=lane&15

  if constexpr (EPI == 0) {
    const bool diag = (rb == cb);
    float rp[8][4] = {};   // [m][e] row partials
    float rpT[4] = {};     // [n]    col partials
#pragma unroll
    for (int m = 0; m < 8; ++m) {
      const int growb = row0 + wr * 128 + m * 16 + e0;
#pragma unroll
      for (int n = 0; n < 4; ++n) {
        const int gcol = col0 + wc * 64 + n * 16 + flane;
        ushort4 mpack;
#pragma unroll
        for (int e = 0; e < 4; ++e) {
          const int grow = growb + e;
          const float ev = (grow == gcol) ? 0.0f : __expf(acc[m][n][e]);
          const uint16_t eb = f2bf(ev);
          const float evr = bf2f(eb);     // sum the ROUNDED value (rows sum to 1)
          Eo[(size_t)grow * NR + gcol] = eb;
          rp[m][e] += evr;
          rpT[n] += evr;
          ((uint16_t*)&mpack)[e] = eb;
        }
        if (!diag)
          *reinterpret_cast<ushort4*>(&Eo[(size_t)gcol * NR + growb]) = mpack;
      }
    }
#pragma unroll
    for (int msk = 1; msk <= 8; msk <<= 1)
#pragma unroll
      for (int m = 0; m < 8; ++m)
#pragma unroll
        for (int e = 0; e < 4; ++e) rp[m][e] += __shfl_xor(rp[m][e], msk, 64);
#pragma unroll
    for (int msk = 16; msk <= 32; msk <<= 1)
#pragma unroll
      for (int n = 0; n < 4; ++n) rpT[n] += __shfl_xor(rpT[n], msk, 64);

    float* sRow = (float*)sm;            // [4][256]
    float* sCol = (float*)(sm + 4096);   // [2][256]
    __syncthreads();
    if (flane == 0) {
#pragma unroll
      for (int m = 0; m < 8; ++m)
#pragma unroll
        for (int e = 0; e < 4; ++e)
          sRow[wc * 256 + wr * 128 + m * 16 + e0 + e] = rp[m][e];
    }
    if (lane < 16) {
#pragma unroll
      for (int n = 0; n < 4; ++n) sCol[wr * 256 + wc * 64 + n * 16 + lane] = rpT[n];
    }
    __syncthreads();
    if (tid < 256) {
      partials[(size_t)cb * NR + row0 + tid] =
          sRow[tid] + sRow[256 + tid] + sRow[512 + tid] + sRow[768 + tid];
      if (!diag)
        partials[(size_t)rb * NR + col0 + tid] = sCol[tid] + sCol[256 + tid];
    }
    __syncthreads();   // (probe: keep LDS reuse safe across reps)
  } else {
#pragma unroll
    for (int m = 0; m < 8; ++m)
#pragma unroll
      for (int n = 0; n < 4; ++n)
#pragma unroll
        for (int e = 0; e < 4; ++e)
          C[(size_t)(row0 + wr * 128 + m * 16 + e0 + e) * ldc +
            col0 + wc * 64 + n * 16 + flane] = acc[m][n][e];
    __syncthreads();
  }
}

// sims GEMM over upper triangle (rb<=cb), 32x32 tiles of 256, XCD-swizzled
// PROBE: reps-loop (idempotent stores) to surface this kernel in rocprof top-5.
__global__ __launch_bounds__(512, 2) void k_gemm_sym8(
    const uint16_t* __restrict__ Xn, uint16_t* __restrict__ E,
    float* __restrict__ partials, int reps) {
  extern __shared__ char smem[];
  const int nwg = gridDim.x;            // 528 = 8*66
  const int cpx = nwg >> 3;
  const int b = blockIdx.x;
  const int swz = (b & 7) * cpx + (b >> 3);
  int rem = swz, rb = 0;
  while (rem >= 32 - rb) { rem -= 32 - rb; ++rb; }
  const int cb = rb + rem;
  for (int r = 0; r < reps; ++r)
    gemm8_core<0, 16>(smem, Xn, ND, Xn, ND, rb * 256, cb * 256,
                      nullptr, 0, E, partials, rb, cb);
}

// PV GEMM: out = E(bf16) . X ; split-K x2, fp32 partials. PROBE: reps-loop.
__global__ __launch_bounds__(512, 2) void k_gemm_pv8(
    const uint16_t* __restrict__ E, const uint16_t* __restrict__ XT,
    float* __restrict__ P, int reps) {
  extern __shared__ char smem[];
  const int b = blockIdx.x;             // 256 = 8*32
  const int swz = (b & 7) * 32 + (b >> 3);
  const int s = swz >> 7;               // K split
  const int t = swz & 127;
  const int by = t >> 2, bx = t & 3;    // 32 x 4 tiles
  for (int r = 0; r < reps; ++r)
    gemm8_core<1, 64>(smem, E + (size_t)s * 4096, NR, XT + (size_t)s * 4096, NR,
                      by * 256, bx * 256, P + (size_t)s * NR * ND, ND,
                      nullptr, nullptr, 0, 0);
}

// ---------------- rowsum: reduce 32 column-block partials ----------------
__global__ void k_rowsum(const float* __restrict__ partials, float* __restrict__ rowsum,
                         int ncb) {
  const int r = blockIdx.x * blockDim.x + threadIdx.x;  // 8192 threads
  float s = 0.0f;
  for (int cb = 0; cb < ncb; ++cb) s += partials[(size_t)cb * NR + r];
  rowsum[r] = s;
}

// ------- fixup: out = (P0 + P1) / rowsum -------
__global__ void k_fixup(const fvec4* __restrict__ P0, const fvec4* __restrict__ P1,
                        const float* __restrict__ rowsum, fvec4* __restrict__ out) {
  const size_t i = (size_t)blockIdx.x * blockDim.x + threadIdx.x;  // float4 units
  const int row = (int)(i >> 8);                                   // /(ND/4)
  const float inv = 1.0f / rowsum[row];
  const fvec4 a = __builtin_nontemporal_load(&P0[i]);
  const fvec4 b = __builtin_nontemporal_load(&P1[i]);
  const fvec4 o = (a + b) * inv;
  __builtin_nontemporal_store(o, &out[i]);
}

// ------- scale: attn(fp32, d_out) = E(bf16) / rowsum -------
__global__ void k_scale(const uint16_t* __restrict__ E, const float* __restrict__ rowsum,
                        float* __restrict__ attn) {
  const size_t total = (size_t)NR * NR / 8;
  for (size_t i = (size_t)blockIdx.x * blockDim.x + threadIdx.x; i < total;
       i += (size_t)gridDim.x * blockDim.x) {
    const int row = (int)(i >> 10);     // (i*8)/8192
    const float inv = 1.0f / rowsum[row];
    const u16x8 e = reinterpret_cast<const u16x8*>(E)[i];   // normal load: E is L3-resident
    fvec4 o0, o1;
    o0.x = bf2f(e[0]) * inv; o0.y = bf2f(e[1]) * inv;
    o0.z = bf2f(e[2]) * inv; o0.w = bf2f(e[3]) * inv;
    o1.x = bf2f(e[4]) * inv; o1.y = bf2f(e[5]) * inv;
    o1.z = bf2f(e[6]) * inv; o1.w = bf2f(e[7]) * inv;
    __builtin_nontemporal_store(o0, &reinterpret_cast<fvec4*>(attn)[2 * i + 0]);
    __builtin_nontemporal_store(o1, &reinterpret_cast<fvec4*>(attn)[2 * i + 1]);
  }
}

extern "C" void kernel_launch(void* const* d_in, const int* in_sizes, int n_in,
                              void* d_out, int out_size, void* d_ws, size_t ws_size,
                              hipStream_t stream) {
  const float* X = (const float*)d_in[0];          // [8192][1024] fp32
  float* out = (float*)d_out;                       // [8192][1024] fp32
  float* attn = out + (size_t)NR * ND;              // [8192][8192] fp32

  char* ws = (char*)d_ws;
  const size_t off_Xn   = 0;                                  // 16 MB bf16 normalized
  const size_t off_XT   = off_Xn + (size_t)NR * ND * 2;       // 16 MB bf16 feats^T
  const size_t off_E    = off_XT + (size_t)ND * NR * 2;       // 128 MB bf16 unscaled exp
  const size_t off_part = off_E + (size_t)NR * NR * 2;        // 2 MB partials
  const size_t off_rs   = off_part + (size_t)64 * NR * 4;     // 32 KB rowsum
  const size_t needed   = off_rs + (size_t)NR * 4;
  if (ws_size < needed) return;

  uint16_t* Xn  = (uint16_t*)(ws + off_Xn);
  uint16_t* XT  = (uint16_t*)(ws + off_XT);
  uint16_t* E   = (uint16_t*)(ws + off_E);
  float* partials = (float*)(ws + off_part);
  float* rowsum   = (float*)(ws + off_rs);

  // PV split-K partials use the (not yet written) attn region of d_out as scratch
  float* P = attn;

  (void)hipFuncSetAttribute((const void*)k_gemm_sym8,
                            hipFuncAttributeMaxDynamicSharedMemorySize, 131072);
  (void)hipFuncSetAttribute((const void*)k_gemm_pv8,
                            hipFuncAttributeMaxDynamicSharedMemorySize, 131072);

  k_norm<<<NR, 256, 0, stream>>>(X, Xn);
  k_transpose<<<(NR / 32) * (ND / 32), 256, 0, stream>>>(X, XT);
  k_gemm_sym8<<<528, 512, 131072, stream>>>(Xn, E, partials, 3);   // PROBE x3
  k_rowsum<<<NR / 256, 256, 0, stream>>>(partials, rowsum, 32);
  k_gemm_pv8<<<256, 512, 131072, stream>>>(E, XT, P, 3);           // PROBE x3
  k_fixup<<<NR * ND / 4 / 256, 256, 0, stream>>>(
      (const fvec4*)P, (const fvec4*)(P + (size_t)NR * ND), rowsum, (fvec4*)out);
  k_scale<<<2048, 256, 0, stream>>>(E, rowsum, attn);
}

// Round 8
// 388.595 us; speedup vs baseline: 3.1802x; 3.1802x over previous
//
#include <hip/hip_runtime.h>
#include <hip/hip_bf16.h>
#include <stdint.h>

#define NR 8192   // rows (N)
#define ND 1024   // feature dim (D)

typedef __attribute__((ext_vector_type(8))) short bf16x8;  // 8 bf16 = 4 VGPR
typedef __attribute__((ext_vector_type(4))) float f32x4;   // MFMA C/D
typedef __attribute__((ext_vector_type(4))) float fvec4;   // ext-vector float4 (nontemporal ok)
typedef __attribute__((ext_vector_type(8))) unsigned short u16x8;

static __device__ __forceinline__ uint16_t f2bf(float f) {
  union { __hip_bfloat16 h; uint16_t u; } cv;
  cv.h = __float2bfloat16(f);
  return cv.u;
}
static __device__ __forceinline__ float bf2f(uint16_t u) {
  union { uint32_t i; float f; } cv;
  cv.i = ((uint32_t)u) << 16;
  return cv.f;
}

// ---------------- kernel 1: row L2 norm -> normalized bf16 ----------------
__global__ void k_norm(const float* __restrict__ X, uint16_t* __restrict__ Xn) {
  const int row = blockIdx.x;
  const int t = threadIdx.x;                    // 256 threads, 4 floats each
  const float4 v = reinterpret_cast<const float4*>(X + (size_t)row * ND)[t];
  float ss = v.x * v.x + v.y * v.y + v.z * v.z + v.w * v.w;
#pragma unroll
  for (int m = 1; m < 64; m <<= 1) ss += __shfl_xor(ss, m, 64);
  __shared__ float sred[4];
  if ((t & 63) == 0) sred[t >> 6] = ss;
  __syncthreads();
  const float tot = sred[0] + sred[1] + sred[2] + sred[3];
  const float inv = 1.0f / fmaxf(sqrtf(tot), 1e-12f);
  ushort4 o;
  o.x = f2bf(v.x * inv); o.y = f2bf(v.y * inv);
  o.z = f2bf(v.z * inv); o.w = f2bf(v.w * inv);
  reinterpret_cast<ushort4*>(Xn + (size_t)row * ND)[t] = o;
}

// ------------- kernel 1b: feats [NR][ND] f32 -> featsT [ND][NR] bf16 -------------
__global__ void k_transpose(const float* __restrict__ X, uint16_t* __restrict__ XT) {
  __shared__ uint16_t tile[32][33];
  const int ntr = NR / 32;                     // 256 row-tiles
  const int bx = blockIdx.x % ntr;             // row-tile of X
  const int by = blockIdx.x / ntr;             // col(dim)-tile of X
  const int r0 = bx * 32, d0 = by * 32;
  const int t = threadIdx.x;                   // 256
  const int rr = t >> 3, cc = (t & 7) * 4;
  const float4 v = *reinterpret_cast<const float4*>(&X[(size_t)(r0 + rr) * ND + d0 + cc]);
  tile[cc + 0][rr] = f2bf(v.x);
  tile[cc + 1][rr] = f2bf(v.y);
  tile[cc + 2][rr] = f2bf(v.z);
  tile[cc + 3][rr] = f2bf(v.w);
  __syncthreads();
  ushort4 o;
  o.x = tile[rr][cc + 0]; o.y = tile[rr][cc + 1];
  o.z = tile[rr][cc + 2]; o.w = tile[rr][cc + 3];
  *reinterpret_cast<ushort4*>(&XT[(size_t)(d0 + rr) * NR + r0 + cc]) = o;
}

// ---------------- 32-MFMA cluster (one M-half x all N x K=64) ----------------
template <int HALF>
static __device__ __forceinline__ void mfma32(f32x4 (&acc)[8][4],
                                              const bf16x8 (&a_)[4][2],
                                              const bf16x8 (&b_)[4][2]) {
  __builtin_amdgcn_s_setprio(1);
#pragma unroll
  for (int kk = 0; kk < 2; ++kk)
#pragma unroll
    for (int m4 = 0; m4 < 4; ++m4)
#pragma unroll
      for (int n = 0; n < 4; ++n)
        acc[HALF * 4 + m4][n] = __builtin_amdgcn_mfma_f32_16x16x32_bf16(
            a_[m4][kk], b_[n][kk], acc[HALF * 4 + m4][n], 0, 0, 0);
  __builtin_amdgcn_s_setprio(0);
}

#define BAR()  __builtin_amdgcn_s_barrier()
#define LGKM() asm volatile("s_waitcnt lgkmcnt(0)" ::: "memory")
#define VMW8() asm volatile("s_waitcnt vmcnt(8)" ::: "memory")
#define VMW0() asm volatile("s_waitcnt vmcnt(0)" ::: "memory")

// ---------------- 256x256 4-phase BT GEMM core ----------------
// C[m][n] = sum_k A[m][k]*B[n][k]
// LDS map (bytes): dbuf d in {0,1}: d*65536 ; A half h: +h*16384 ; B: +32768+h*16384
// half-tile = [128 rows][64 k] bf16, 128B rows, stored in 16B chunks (8/row).
// QUARTER-WAVE bank swizzle: data chunk c of row r lives at LDS chunk c ^ (r&7).
//  - read: chunk = ((lane>>4) + kk*4) ^ (flane&7)  -> each 16-lane quarter covers
//    all 8 chunks (32 banks) at 2 lanes/bank (free).  [R7 probe: old layout had
//    whole quarters on 4 banks -> 1.26e7 conflicts/dispatch, MfmaUtil 26%]
//  - stage: linear LDS dest (rule #21), source col pre-swizzled with the same
//    involution: colb = ((tid&7) ^ ((tid>>3)&7))*16  (dest row&7 == (tid>>3)&7).
template <int EPI, int NKT>
static __device__ __forceinline__ void gemm8_core(
    char* sm,
    const uint16_t* __restrict__ A, int lda,
    const uint16_t* __restrict__ B, int ldb,
    int row0, int col0,
    float* __restrict__ C, int ldc,
    uint16_t* __restrict__ Eo, float* __restrict__ partials, int rb, int cb) {
  const int tid = threadIdx.x;
  const int wid = tid >> 6;
  const int lane = tid & 63;
  const int wr = wid >> 2;            // 0..1  (M wave)
  const int wc = wid & 3;             // 0..3  (N wave)
  const int flane = lane & 15;
  const int qw = lane >> 4;           // quarter-wave index -> k chunk base
  const int rkey = flane & 7;         // row&7 swizzle key
  const int rowb = flane * 128;

  // staging source geometry (inverse-swizzled global source, linear LDS dest)
  const int colb = (((tid & 7) ^ ((tid >> 3) & 7)) * 16);
  const int r0s = tid >> 3;           // row for load g0; g1 adds 64

  const char* const Abyte = (const char*)A + (size_t)row0 * lda * 2;
  const char* const Bbyte = (const char*)B + (size_t)col0 * ldb * 2;

  f32x4 acc[8][4] = {};
  bf16x8 a_[4][2], b_[4][2];

  auto stage = [&](int d, int isB, int h, int t) {
    const char* gb = isB ? Bbyte : Abyte;
    const int ld2 = (isB ? ldb : lda) * 2;
    const char* g0 = gb + (size_t)(h * 128 + r0s) * ld2 + t * 128 + colb;
    const char* g1 = g0 + (size_t)64 * ld2;
    char* l0 = sm + d * 65536 + isB * 32768 + h * 16384 + (wid << 10);
    __builtin_amdgcn_global_load_lds((const __attribute__((address_space(1))) void*)g0,
                                     (__attribute__((address_space(3))) void*)l0, 16, 0, 0);
    __builtin_amdgcn_global_load_lds((const __attribute__((address_space(1))) void*)g1,
                                     (__attribute__((address_space(3))) void*)(l0 + 8192), 16, 0, 0);
  };
  auto stage4 = [&](int d, int t) {
    stage(d, 0, 0, t); stage(d, 0, 1, t); stage(d, 1, 0, t); stage(d, 1, 1, t);
  };
  auto rdA = [&](int d, int mhalf) {
#pragma unroll
    for (int m4 = 0; m4 < 4; ++m4)
#pragma unroll
      for (int kk = 0; kk < 2; ++kk) {
        const int chunk = (qw + kk * 4) ^ rkey;
        a_[m4][kk] = *(const bf16x8*)(sm + d * 65536 + wr * 16384 +
                                      (mhalf * 4 + m4) * 2048 + rowb + chunk * 16);
      }
  };
  auto rdB = [&](int d) {
#pragma unroll
    for (int n = 0; n < 4; ++n)
#pragma unroll
      for (int kk = 0; kk < 2; ++kk) {
        const int chunk = (qw + kk * 4) ^ rkey;
        b_[n][kk] = *(const bf16x8*)(sm + d * 65536 + 32768 + (wc >> 1) * 16384 +
                                     (wc & 1) * 8192 + n * 2048 + rowb + chunk * 16);
      }
  };

  // prologue: stage d0 <- K-tile 0 (8 load instrs in flight)
  stage4(0, 0);

  const int niter = NKT / 2;
  for (int i = 0; i < niter; ++i) {
    const int t0 = 2 * i, t1 = 2 * i + 1;
    // P1
    stage4(1, t1);
    VMW8();           // wait d0 landed (keep d1's 8 loads in flight)
    BAR();            // publish d0 across waves
    rdA(0, 0); rdB(0);
    LGKM(); mfma32<0>(acc, a_, b_); BAR();
    // P2
    rdA(0, 1);
    LGKM(); mfma32<1>(acc, a_, b_); BAR();
    // P3
    if (t0 + 2 < NKT) { stage4(0, t0 + 2); VMW8(); }
    else { VMW0(); }
    BAR();            // publish d1
    rdA(1, 0); rdB(1);
    LGKM(); mfma32<0>(acc, a_, b_); BAR();
    // P4
    rdA(1, 1);
    LGKM(); mfma32<1>(acc, a_, b_); BAR();
  }

  const int e0 = (lane >> 4) * 4;   // C/D: row=(lane>>4)*4+e, col=lane&15

  if constexpr (EPI == 0) {
    const bool diag = (rb == cb);
    float rp[8][4] = {};   // [m][e] row partials
    float rpT[4] = {};     // [n]    col partials
#pragma unroll
    for (int m = 0; m < 8; ++m) {
      const int growb = row0 + wr * 128 + m * 16 + e0;
#pragma unroll
      for (int n = 0; n < 4; ++n) {
        const int gcol = col0 + wc * 64 + n * 16 + flane;
        ushort4 mpack;
#pragma unroll
        for (int e = 0; e < 4; ++e) {
          const int grow = growb + e;
          const float ev = (grow == gcol) ? 0.0f : __expf(acc[m][n][e]);
          const uint16_t eb = f2bf(ev);
          const float evr = bf2f(eb);     // sum the ROUNDED value (rows sum to 1)
          Eo[(size_t)grow * NR + gcol] = eb;
          rp[m][e] += evr;
          rpT[n] += evr;
          ((uint16_t*)&mpack)[e] = eb;
        }
        if (!diag)
          *reinterpret_cast<ushort4*>(&Eo[(size_t)gcol * NR + growb]) = mpack;
      }
    }
#pragma unroll
    for (int msk = 1; msk <= 8; msk <<= 1)
#pragma unroll
      for (int m = 0; m < 8; ++m)
#pragma unroll
        for (int e = 0; e < 4; ++e) rp[m][e] += __shfl_xor(rp[m][e], msk, 64);
#pragma unroll
    for (int msk = 16; msk <= 32; msk <<= 1)
#pragma unroll
      for (int n = 0; n < 4; ++n) rpT[n] += __shfl_xor(rpT[n], msk, 64);

    float* sRow = (float*)sm;            // [4][256]
    float* sCol = (float*)(sm + 4096);   // [2][256]
    __syncthreads();
    if (flane == 0) {
#pragma unroll
      for (int m = 0; m < 8; ++m)
#pragma unroll
        for (int e = 0; e < 4; ++e)
          sRow[wc * 256 + wr * 128 + m * 16 + e0 + e] = rp[m][e];
    }
    if (lane < 16) {
#pragma unroll
      for (int n = 0; n < 4; ++n) sCol[wr * 256 + wc * 64 + n * 16 + lane] = rpT[n];
    }
    __syncthreads();
    if (tid < 256) {
      partials[(size_t)cb * NR + row0 + tid] =
          sRow[tid] + sRow[256 + tid] + sRow[512 + tid] + sRow[768 + tid];
      if (!diag)
        partials[(size_t)rb * NR + col0 + tid] = sCol[tid] + sCol[256 + tid];
    }
  } else {
#pragma unroll
    for (int m = 0; m < 8; ++m)
#pragma unroll
      for (int n = 0; n < 4; ++n)
#pragma unroll
        for (int e = 0; e < 4; ++e)
          C[(size_t)(row0 + wr * 128 + m * 16 + e0 + e) * ldc +
            col0 + wc * 64 + n * 16 + flane] = acc[m][n][e];
  }
}

// sims GEMM over upper triangle (rb<=cb), 32x32 tiles of 256, XCD-swizzled
__global__ __launch_bounds__(512, 2) void k_gemm_sym8(
    const uint16_t* __restrict__ Xn, uint16_t* __restrict__ E,
    float* __restrict__ partials) {
  extern __shared__ char smem[];
  const int nwg = gridDim.x;            // 528 = 8*66
  const int cpx = nwg >> 3;
  const int b = blockIdx.x;
  const int swz = (b & 7) * cpx + (b >> 3);
  int rem = swz, rb = 0;
  while (rem >= 32 - rb) { rem -= 32 - rb; ++rb; }
  const int cb = rb + rem;
  gemm8_core<0, 16>(smem, Xn, ND, Xn, ND, rb * 256, cb * 256,
                    nullptr, 0, E, partials, rb, cb);
}

// PV GEMM: out = E(bf16) . X ; split-K x2, fp32 partials
__global__ __launch_bounds__(512, 2) void k_gemm_pv8(
    const uint16_t* __restrict__ E, const uint16_t* __restrict__ XT,
    float* __restrict__ P) {
  extern __shared__ char smem[];
  const int b = blockIdx.x;             // 256 = 8*32
  const int swz = (b & 7) * 32 + (b >> 3);
  const int s = swz >> 7;               // K split
  const int t = swz & 127;
  const int by = t >> 2, bx = t & 3;    // 32 x 4 tiles
  gemm8_core<1, 64>(smem, E + (size_t)s * 4096, NR, XT + (size_t)s * 4096, NR,
                    by * 256, bx * 256, P + (size_t)s * NR * ND, ND,
                    nullptr, nullptr, 0, 0);
}

// ---------------- rowsum: reduce 32 column-block partials ----------------
__global__ void k_rowsum(const float* __restrict__ partials, float* __restrict__ rowsum,
                         int ncb) {
  const int r = blockIdx.x * blockDim.x + threadIdx.x;  // 8192 threads
  float s = 0.0f;
  for (int cb = 0; cb < ncb; ++cb) s += partials[(size_t)cb * NR + r];
  rowsum[r] = s;
}

// ------- fixup: out = (P0 + P1) / rowsum -------
__global__ void k_fixup(const fvec4* __restrict__ P0, const fvec4* __restrict__ P1,
                        const float* __restrict__ rowsum, fvec4* __restrict__ out) {
  const size_t i = (size_t)blockIdx.x * blockDim.x + threadIdx.x;  // float4 units
  const int row = (int)(i >> 8);                                   // /(ND/4)
  const float inv = 1.0f / rowsum[row];
  const fvec4 a = __builtin_nontemporal_load(&P0[i]);
  const fvec4 b = __builtin_nontemporal_load(&P1[i]);
  const fvec4 o = (a + b) * inv;
  __builtin_nontemporal_store(o, &out[i]);
}

// ------- scale: attn(fp32, d_out) = E(bf16) / rowsum -------
__global__ void k_scale(const uint16_t* __restrict__ E, const float* __restrict__ rowsum,
                        float* __restrict__ attn) {
  const size_t total = (size_t)NR * NR / 8;
  for (size_t i = (size_t)blockIdx.x * blockDim.x + threadIdx.x; i < total;
       i += (size_t)gridDim.x * blockDim.x) {
    const int row = (int)(i >> 10);     // (i*8)/8192
    const float inv = 1.0f / rowsum[row];
    const u16x8 e = reinterpret_cast<const u16x8*>(E)[i];   // normal load: E is L3-resident
    fvec4 o0, o1;
    o0.x = bf2f(e[0]) * inv; o0.y = bf2f(e[1]) * inv;
    o0.z = bf2f(e[2]) * inv; o0.w = bf2f(e[3]) * inv;
    o1.x = bf2f(e[4]) * inv; o1.y = bf2f(e[5]) * inv;
    o1.z = bf2f(e[6]) * inv; o1.w = bf2f(e[7]) * inv;
    __builtin_nontemporal_store(o0, &reinterpret_cast<fvec4*>(attn)[2 * i + 0]);
    __builtin_nontemporal_store(o1, &reinterpret_cast<fvec4*>(attn)[2 * i + 1]);
  }
}

extern "C" void kernel_launch(void* const* d_in, const int* in_sizes, int n_in,
                              void* d_out, int out_size, void* d_ws, size_t ws_size,
                              hipStream_t stream) {
  const float* X = (const float*)d_in[0];          // [8192][1024] fp32
  float* out = (float*)d_out;                       // [8192][1024] fp32
  float* attn = out + (size_t)NR * ND;              // [8192][8192] fp32

  char* ws = (char*)d_ws;
  const size_t off_Xn   = 0;                                  // 16 MB bf16 normalized
  const size_t off_XT   = off_Xn + (size_t)NR * ND * 2;       // 16 MB bf16 feats^T
  const size_t off_E    = off_XT + (size_t)ND * NR * 2;       // 128 MB bf16 unscaled exp
  const size_t off_part = off_E + (size_t)NR * NR * 2;        // 2 MB partials
  const size_t off_rs   = off_part + (size_t)64 * NR * 4;     // 32 KB rowsum
  const size_t needed   = off_rs + (size_t)NR * 4;
  if (ws_size < needed) return;

  uint16_t* Xn  = (uint16_t*)(ws + off_Xn);
  uint16_t* XT  = (uint16_t*)(ws + off_XT);
  uint16_t* E   = (uint16_t*)(ws + off_E);
  float* partials = (float*)(ws + off_part);
  float* rowsum   = (float*)(ws + off_rs);

  // PV split-K partials use the (not yet written) attn region of d_out as scratch
  float* P = attn;

  (void)hipFuncSetAttribute((const void*)k_gemm_sym8,
                            hipFuncAttributeMaxDynamicSharedMemorySize, 131072);
  (void)hipFuncSetAttribute((const void*)k_gemm_pv8,
                            hipFuncAttributeMaxDynamicSharedMemorySize, 131072);

  k_norm<<<NR, 256, 0, stream>>>(X, Xn);
  k_transpose<<<(NR / 32) * (ND / 32), 256, 0, stream>>>(X, XT);
  k_gemm_sym8<<<528, 512, 131072, stream>>>(Xn, E, partials);
  k_rowsum<<<NR / 256, 256, 0, stream>>>(partials, rowsum, 32);
  k_gemm_pv8<<<256, 512, 131072, stream>>>(E, XT, P);
  k_fixup<<<NR * ND / 4 / 256, 256, 0, stream>>>(
      (const fvec4*)P, (const fvec4*)(P + (size_t)NR * ND), rowsum, (fvec4*)out);
  k_scale<<<2048, 256, 0, stream>>>(E, rowsum, attn);
}

// Round 9
// 373.556 us; speedup vs baseline: 3.3083x; 1.0403x over previous
//
#include <hip/hip_runtime.h>
#include <hip/hip_bf16.h>
#include <stdint.h>

#define NR 8192   // rows (N)
#define ND 1024   // feature dim (D)

typedef __attribute__((ext_vector_type(8))) short bf16x8;  // 8 bf16 = 4 VGPR
typedef __attribute__((ext_vector_type(4))) float f32x4;   // MFMA C/D
typedef __attribute__((ext_vector_type(4))) float fvec4;   // ext-vector float4 (nontemporal ok)
typedef __attribute__((ext_vector_type(8))) unsigned short u16x8;

static __device__ __forceinline__ uint16_t f2bf(float f) {
  union { __hip_bfloat16 h; uint16_t u; } cv;
  cv.h = __float2bfloat16(f);
  return cv.u;
}
static __device__ __forceinline__ float bf2f(uint16_t u) {
  union { uint32_t i; float f; } cv;
  cv.i = ((uint32_t)u) << 16;
  return cv.f;
}

// ---------------- kernel 1: row L2 norm -> normalized bf16 ----------------
__global__ void k_norm(const float* __restrict__ X, uint16_t* __restrict__ Xn) {
  const int row = blockIdx.x;
  const int t = threadIdx.x;                    // 256 threads, 4 floats each
  const float4 v = reinterpret_cast<const float4*>(X + (size_t)row * ND)[t];
  float ss = v.x * v.x + v.y * v.y + v.z * v.z + v.w * v.w;
#pragma unroll
  for (int m = 1; m < 64; m <<= 1) ss += __shfl_xor(ss, m, 64);
  __shared__ float sred[4];
  if ((t & 63) == 0) sred[t >> 6] = ss;
  __syncthreads();
  const float tot = sred[0] + sred[1] + sred[2] + sred[3];
  const float inv = 1.0f / fmaxf(sqrtf(tot), 1e-12f);
  ushort4 o;
  o.x = f2bf(v.x * inv); o.y = f2bf(v.y * inv);
  o.z = f2bf(v.z * inv); o.w = f2bf(v.w * inv);
  reinterpret_cast<ushort4*>(Xn + (size_t)row * ND)[t] = o;
}

// ------------- kernel 1b: feats [NR][ND] f32 -> featsT [ND][NR] bf16 -------------
__global__ void k_transpose(const float* __restrict__ X, uint16_t* __restrict__ XT) {
  __shared__ uint16_t tile[32][33];
  const int ntr = NR / 32;                     // 256 row-tiles
  const int bx = blockIdx.x % ntr;             // row-tile of X
  const int by = blockIdx.x / ntr;             // col(dim)-tile of X
  const int r0 = bx * 32, d0 = by * 32;
  const int t = threadIdx.x;                   // 256
  const int rr = t >> 3, cc = (t & 7) * 4;
  const float4 v = *reinterpret_cast<const float4*>(&X[(size_t)(r0 + rr) * ND + d0 + cc]);
  tile[cc + 0][rr] = f2bf(v.x);
  tile[cc + 1][rr] = f2bf(v.y);
  tile[cc + 2][rr] = f2bf(v.z);
  tile[cc + 3][rr] = f2bf(v.w);
  __syncthreads();
  ushort4 o;
  o.x = tile[rr][cc + 0]; o.y = tile[rr][cc + 1];
  o.z = tile[rr][cc + 2]; o.w = tile[rr][cc + 3];
  *reinterpret_cast<ushort4*>(&XT[(size_t)(d0 + rr) * NR + r0 + cc]) = o;
}

// ---------------- 32-MFMA cluster (one M-half x all N x K=64) ----------------
template <int HALF>
static __device__ __forceinline__ void mfma32(f32x4 (&acc)[8][4],
                                              const bf16x8 (&a_)[4][2],
                                              const bf16x8 (&b_)[4][2]) {
  __builtin_amdgcn_s_setprio(1);
#pragma unroll
  for (int kk = 0; kk < 2; ++kk)
#pragma unroll
    for (int m4 = 0; m4 < 4; ++m4)
#pragma unroll
      for (int n = 0; n < 4; ++n)
        acc[HALF * 4 + m4][n] = __builtin_amdgcn_mfma_f32_16x16x32_bf16(
            a_[m4][kk], b_[n][kk], acc[HALF * 4 + m4][n], 0, 0, 0);
  __builtin_amdgcn_s_setprio(0);
}

#define BAR()    __builtin_amdgcn_s_barrier()
#define LGKM()   asm volatile("s_waitcnt lgkmcnt(0)" ::: "memory")
#define VMW8()   asm volatile("s_waitcnt vmcnt(8)" ::: "memory")
#define VMW0()   asm volatile("s_waitcnt vmcnt(0)" ::: "memory")
#define SCHED0() __builtin_amdgcn_sched_barrier(0)

// ---------------- 256x256 de-lockstepped BT GEMM core ----------------
// C[m][n] = sum_k A[m][k]*B[n][k]
// LDS map (bytes): dbuf d in {0,1}: d*65536 ; A half h: +h*16384 ; B: +32768+h*16384
// half-tile = [128 rows][64 k] bf16, 128B rows, stored in 16B chunks (8/row).
// Quarter-wave bank swizzle (R8, conflict-free): data chunk c of row r lives at
// LDS chunk c ^ (r&7); stage source col pre-swizzled with the same involution.
// K-loop (R9): 2 barriers per K-tile ONLY (reads-done / publish). Within a K-tile
// each wave runs {16 ds_read; lgkm0; 32 MFMA; 8 ds_read; lgkm0; 32 MFMA} on its own
// clock -> waves drift, MFMA of one wave covers LDS-wait of another (T5 applies).
template <int EPI, int NKT>
static __device__ __forceinline__ void gemm8_core(
    char* sm,
    const uint16_t* __restrict__ A, int lda,
    const uint16_t* __restrict__ B, int ldb,
    int row0, int col0,
    float* __restrict__ C, int ldc,
    uint16_t* __restrict__ Eo, float* __restrict__ partials, int rb, int cb) {
  const int tid = threadIdx.x;
  const int wid = tid >> 6;
  const int lane = tid & 63;
  const int wr = wid >> 2;            // 0..1  (M wave)
  const int wc = wid & 3;             // 0..3  (N wave)
  const int flane = lane & 15;
  const int qw = lane >> 4;           // quarter-wave index -> k chunk base
  const int rkey = flane & 7;         // row&7 swizzle key
  const int rowb = flane * 128;

  // staging source geometry (inverse-swizzled global source, linear LDS dest)
  const int colb = (((tid & 7) ^ ((tid >> 3) & 7)) * 16);
  const int r0s = tid >> 3;           // row for load g0; g1 adds 64

  const char* const Abyte = (const char*)A + (size_t)row0 * lda * 2;
  const char* const Bbyte = (const char*)B + (size_t)col0 * ldb * 2;

  f32x4 acc[8][4] = {};
  bf16x8 a_[4][2], b_[4][2];

  auto stage = [&](int d, int isB, int h, int t) {
    const char* gb = isB ? Bbyte : Abyte;
    const int ld2 = (isB ? ldb : lda) * 2;
    const char* g0 = gb + (size_t)(h * 128 + r0s) * ld2 + t * 128 + colb;
    const char* g1 = g0 + (size_t)64 * ld2;
    char* l0 = sm + d * 65536 + isB * 32768 + h * 16384 + (wid << 10);
    __builtin_amdgcn_global_load_lds((const __attribute__((address_space(1))) void*)g0,
                                     (__attribute__((address_space(3))) void*)l0, 16, 0, 0);
    __builtin_amdgcn_global_load_lds((const __attribute__((address_space(1))) void*)g1,
                                     (__attribute__((address_space(3))) void*)(l0 + 8192), 16, 0, 0);
  };
  auto stage4 = [&](int d, int t) {
    stage(d, 0, 0, t); stage(d, 0, 1, t); stage(d, 1, 0, t); stage(d, 1, 1, t);
  };
  auto rdA = [&](int d, int mhalf) {
#pragma unroll
    for (int m4 = 0; m4 < 4; ++m4)
#pragma unroll
      for (int kk = 0; kk < 2; ++kk) {
        const int chunk = (qw + kk * 4) ^ rkey;
        a_[m4][kk] = *(const bf16x8*)(sm + d * 65536 + wr * 16384 +
                                      (mhalf * 4 + m4) * 2048 + rowb + chunk * 16);
      }
  };
  auto rdB = [&](int d) {
#pragma unroll
    for (int n = 0; n < 4; ++n)
#pragma unroll
      for (int kk = 0; kk < 2; ++kk) {
        const int chunk = (qw + kk * 4) ^ rkey;
        b_[n][kk] = *(const bf16x8*)(sm + d * 65536 + 32768 + (wc >> 1) * 16384 +
                                     (wc & 1) * 8192 + n * 2048 + rowb + chunk * 16);
      }
  };

  // one K-tile: 16 reads -> MFMA<0> ; 8 reads -> MFMA<1>
  auto ktile = [&](int d) {
    rdB(d); rdA(d, 0);
    LGKM(); SCHED0();
    mfma32<0>(acc, a_, b_);
    rdA(d, 1);
    LGKM(); SCHED0();
    mfma32<1>(acc, a_, b_);
  };

  // prologue: d0 <- tile0, d1 <- tile1 (16 loads in flight), publish d0
  stage4(0, 0);
  stage4(1, 1);
  VMW8();            // d0's 8 loads landed (keep d1's in flight)
  BAR();             // publish d0

  const int niter = NKT / 2;
  for (int i = 0; i < niter; ++i) {
    const int t0 = 2 * i, t1 = t0 + 1;
    // ---- tile t0 from d0 ----
    ktile(0);
    BAR();                         // all waves done reading d0
    if (t0 + 2 < NKT) { stage4(0, t0 + 2); VMW8(); }
    else              { VMW0(); }  // tail: wait d1 fully landed
    BAR();                         // publish d1
    // ---- tile t1 from d1 ----
    ktile(1);
    BAR();                         // all waves done reading d1
    if (t1 + 2 < NKT) { stage4(1, t1 + 2); VMW8(); }
    else if (t1 + 1 < NKT) { VMW0(); }
    BAR();                         // publish d0 (next iteration)
  }

  const int e0 = (lane >> 4) * 4;   // C/D: row=(lane>>4)*4+e, col=lane&15

  if constexpr (EPI == 0) {
    const bool diag = (rb == cb);
    float rp[8][4] = {};   // [m][e] row partials
    float rpT[4] = {};     // [n]    col partials
    // mirror image in LDS: uint16 [mr 256][mc 256]; byte = mr*512+mc*2 ^ ((mr&7)<<4)
#pragma unroll
    for (int m = 0; m < 8; ++m) {
      const int growb = row0 + wr * 128 + m * 16 + e0;
#pragma unroll
      for (int n = 0; n < 4; ++n) {
        const int gcol = col0 + wc * 64 + n * 16 + flane;
        ushort4 mpack;
#pragma unroll
        for (int e = 0; e < 4; ++e) {
          const int grow = growb + e;
          const float ev = (grow == gcol) ? 0.0f : __expf(acc[m][n][e]);
          const uint16_t eb = f2bf(ev);
          const float evr = bf2f(eb);     // sum the ROUNDED value (rows sum to 1)
          Eo[(size_t)grow * NR + gcol] = eb;
          rp[m][e] += evr;
          rpT[n] += evr;
          ((uint16_t*)&mpack)[e] = eb;
        }
        if (!diag) {
          const int mr = wc * 64 + n * 16 + flane;     // mirror row (block-local)
          const int mc = wr * 128 + m * 16 + e0;       // mirror col base (4 vals)
          int byte = mr * 512 + mc * 2;
          byte ^= (mr & 7) << 4;                       // 16B-granule XOR, 8B-aligned ok
          *reinterpret_cast<ushort4*>(sm + byte) = mpack;
        }
      }
    }
#pragma unroll
    for (int msk = 1; msk <= 8; msk <<= 1)
#pragma unroll
      for (int m = 0; m < 8; ++m)
#pragma unroll
        for (int e = 0; e < 4; ++e) rp[m][e] += __shfl_xor(rp[m][e], msk, 64);
#pragma unroll
    for (int msk = 16; msk <= 32; msk <<= 1)
#pragma unroll
      for (int n = 0; n < 4; ++n) rpT[n] += __shfl_xor(rpT[n], msk, 64);

    __syncthreads();   // mirror image complete
    if (!diag) {
      // coalesced mirror store: 16 passes x (16 rows x 32 chunks of 16B)
#pragma unroll
      for (int p = 0; p < 16; ++p) {
        const int mr = p * 16 + (tid >> 5);
        const int ch = tid & 31;
        int byte = mr * 512 + ch * 16;
        byte ^= (mr & 7) << 4;
        const u16x8 v = *reinterpret_cast<const u16x8*>(sm + byte);
        *reinterpret_cast<u16x8*>(&Eo[(size_t)(col0 + mr) * NR + row0 + ch * 8]) = v;
      }
    }
    __syncthreads();   // LDS free for partials scratch

    float* sRow = (float*)sm;            // [4][256]
    float* sCol = (float*)(sm + 4096);   // [2][256]
    if (flane == 0) {
#pragma unroll
      for (int m = 0; m < 8; ++m)
#pragma unroll
        for (int e = 0; e < 4; ++e)
          sRow[wc * 256 + wr * 128 + m * 16 + e0 + e] = rp[m][e];
    }
    if (lane < 16) {
#pragma unroll
      for (int n = 0; n < 4; ++n) sCol[wr * 256 + wc * 64 + n * 16 + lane] = rpT[n];
    }
    __syncthreads();
    if (tid < 256) {
      partials[(size_t)cb * NR + row0 + tid] =
          sRow[tid] + sRow[256 + tid] + sRow[512 + tid] + sRow[768 + tid];
      if (!diag)
        partials[(size_t)rb * NR + col0 + tid] = sCol[tid] + sCol[256 + tid];
    }
  } else {
#pragma unroll
    for (int m = 0; m < 8; ++m)
#pragma unroll
      for (int n = 0; n < 4; ++n)
#pragma unroll
        for (int e = 0; e < 4; ++e)
          C[(size_t)(row0 + wr * 128 + m * 16 + e0 + e) * ldc +
            col0 + wc * 64 + n * 16 + flane] = acc[m][n][e];
  }
}

// sims GEMM over upper triangle (rb<=cb), 32x32 tiles of 256, XCD-swizzled
__global__ __launch_bounds__(512, 2) void k_gemm_sym8(
    const uint16_t* __restrict__ Xn, uint16_t* __restrict__ E,
    float* __restrict__ partials) {
  extern __shared__ char smem[];
  const int nwg = gridDim.x;            // 528 = 8*66
  const int cpx = nwg >> 3;
  const int b = blockIdx.x;
  const int swz = (b & 7) * cpx + (b >> 3);
  int rem = swz, rb = 0;
  while (rem >= 32 - rb) { rem -= 32 - rb; ++rb; }
  const int cb = rb + rem;
  gemm8_core<0, 16>(smem, Xn, ND, Xn, ND, rb * 256, cb * 256,
                    nullptr, 0, E, partials, rb, cb);
}

// PV GEMM: out = E(bf16) . X ; split-K x2, fp32 partials
__global__ __launch_bounds__(512, 2) void k_gemm_pv8(
    const uint16_t* __restrict__ E, const uint16_t* __restrict__ XT,
    float* __restrict__ P) {
  extern __shared__ char smem[];
  const int b = blockIdx.x;             // 256 = 8*32
  const int swz = (b & 7) * 32 + (b >> 3);
  const int s = swz >> 7;               // K split
  const int t = swz & 127;
  const int by = t >> 2, bx = t & 3;    // 32 x 4 tiles
  gemm8_core<1, 64>(smem, E + (size_t)s * 4096, NR, XT + (size_t)s * 4096, NR,
                    by * 256, bx * 256, P + (size_t)s * NR * ND, ND,
                    nullptr, nullptr, 0, 0);
}

// ---------------- rowsum: reduce 32 column-block partials ----------------
__global__ void k_rowsum(const float* __restrict__ partials, float* __restrict__ rowsum,
                         int ncb) {
  const int r = blockIdx.x * blockDim.x + threadIdx.x;  // 8192 threads
  float s = 0.0f;
  for (int cb = 0; cb < ncb; ++cb) s += partials[(size_t)cb * NR + r];
  rowsum[r] = s;
}

// ------- fixup: out = (P0 + P1) / rowsum -------
__global__ void k_fixup(const fvec4* __restrict__ P0, const fvec4* __restrict__ P1,
                        const float* __restrict__ rowsum, fvec4* __restrict__ out) {
  const size_t i = (size_t)blockIdx.x * blockDim.x + threadIdx.x;  // float4 units
  const int row = (int)(i >> 8);                                   // /(ND/4)
  const float inv = 1.0f / rowsum[row];
  const fvec4 a = __builtin_nontemporal_load(&P0[i]);
  const fvec4 b = __builtin_nontemporal_load(&P1[i]);
  const fvec4 o = (a + b) * inv;
  __builtin_nontemporal_store(o, &out[i]);
}

// ------- scale: attn(fp32, d_out) = E(bf16) / rowsum -------
__global__ void k_scale(const uint16_t* __restrict__ E, const float* __restrict__ rowsum,
                        float* __restrict__ attn) {
  const size_t total = (size_t)NR * NR / 8;
  for (size_t i = (size_t)blockIdx.x * blockDim.x + threadIdx.x; i < total;
       i += (size_t)gridDim.x * blockDim.x) {
    const int row = (int)(i >> 10);     // (i*8)/8192
    const float inv = 1.0f / rowsum[row];
    const u16x8 e = reinterpret_cast<const u16x8*>(E)[i];   // normal load: E is L3-resident
    fvec4 o0, o1;
    o0.x = bf2f(e[0]) * inv; o0.y = bf2f(e[1]) * inv;
    o0.z = bf2f(e[2]) * inv; o0.w = bf2f(e[3]) * inv;
    o1.x = bf2f(e[4]) * inv; o1.y = bf2f(e[5]) * inv;
    o1.z = bf2f(e[6]) * inv; o1.w = bf2f(e[7]) * inv;
    __builtin_nontemporal_store(o0, &reinterpret_cast<fvec4*>(attn)[2 * i + 0]);
    __builtin_nontemporal_store(o1, &reinterpret_cast<fvec4*>(attn)[2 * i + 1]);
  }
}

extern "C" void kernel_launch(void* const* d_in, const int* in_sizes, int n_in,
                              void* d_out, int out_size, void* d_ws, size_t ws_size,
                              hipStream_t stream) {
  const float* X = (const float*)d_in[0];          // [8192][1024] fp32
  float* out = (float*)d_out;                       // [8192][1024] fp32
  float* attn = out + (size_t)NR * ND;              // [8192][8192] fp32

  char* ws = (char*)d_ws;
  const size_t off_Xn   = 0;                                  // 16 MB bf16 normalized
  const size_t off_XT   = off_Xn + (size_t)NR * ND * 2;       // 16 MB bf16 feats^T
  const size_t off_E    = off_XT + (size_t)ND * NR * 2;       // 128 MB bf16 unscaled exp
  const size_t off_part = off_E + (size_t)NR * NR * 2;        // 2 MB partials
  const size_t off_rs   = off_part + (size_t)64 * NR * 4;     // 32 KB rowsum
  const size_t needed   = off_rs + (size_t)NR * 4;
  if (ws_size < needed) return;

  uint16_t* Xn  = (uint16_t*)(ws + off_Xn);
  uint16_t* XT  = (uint16_t*)(ws + off_XT);
  uint16_t* E   = (uint16_t*)(ws + off_E);
  float* partials = (float*)(ws + off_part);
  float* rowsum   = (float*)(ws + off_rs);

  // PV split-K partials use the (not yet written) attn region of d_out as scratch
  float* P = attn;

  (void)hipFuncSetAttribute((const void*)k_gemm_sym8,
                            hipFuncAttributeMaxDynamicSharedMemorySize, 131072);
  (void)hipFuncSetAttribute((const void*)k_gemm_pv8,
                            hipFuncAttributeMaxDynamicSharedMemorySize, 131072);

  k_norm<<<NR, 256, 0, stream>>>(X, Xn);
  k_transpose<<<(NR / 32) * (ND / 32), 256, 0, stream>>>(X, XT);
  k_gemm_sym8<<<528, 512, 131072, stream>>>(Xn, E, partials);
  k_rowsum<<<NR / 256, 256, 0, stream>>>(partials, rowsum, 32);
  k_gemm_pv8<<<256, 512, 131072, stream>>>(E, XT, P);
  k_fixup<<<NR * ND / 4 / 256, 256, 0, stream>>>(
      (const fvec4*)P, (const fvec4*)(P + (size_t)NR * ND), rowsum, (fvec4*)out);
  k_scale<<<2048, 256, 0, stream>>>(E, rowsum, attn);
}